// Round 14
// baseline (360.385 us; speedup 1.0000x reference)
//
#include <hip/hip_runtime.h>
#include <hip/hip_bf16.h>

#define E 256
#define H 16
#define DD 16
#define FFH 512
#define LAYERS 5
#define BB 4
#define NN 256
#define MROWS 1024  // B*N

typedef __attribute__((ext_vector_type(8))) short bfrag;
typedef __attribute__((ext_vector_type(4))) float f32x4;
typedef __attribute__((ext_vector_type(8))) unsigned short us8;
typedef unsigned short u16;

__device__ __forceinline__ void bsplit(float v, u16& h, u16& l) {
    unsigned u = __float_as_uint(v);
    u16 hh = (u16)((u + 0x7fffu + ((u >> 16) & 1u)) >> 16);
    float r = v - __uint_as_float((unsigned)hh << 16);
    unsigned u2 = __float_as_uint(r);
    h = hh;
    l = (u16)((u2 + 0x7fffu + ((u2 >> 16) & 1u)) >> 16);
}

// ================= fused prep (minmax | emb | dataT | wprep | mixconst) =================
union PrepS {
    float tile[32 * 33];
    struct { u16 th[64 * 40], tl[64 * 40]; } wp;
    struct { float smin[4], smax[4]; } mm;
};

__global__ __launch_bounds__(256) void k_prep(
    const float* __restrict__ data, const float* __restrict__ node_rand,
    const float* __restrict__ Wnode, const float* __restrict__ bnode,
    const float* __restrict__ Wedge, const float* __restrict__ bedge,
    const float* __restrict__ Wmix,
    const float* __restrict__ Wq, const float* __restrict__ Wk, const float* __restrict__ Wv,
    const float* __restrict__ Wc, const float* __restrict__ W1, const float* __restrict__ W2,
    float* __restrict__ pmin, float* __restrict__ pmax, float* __restrict__ c1c0,
    float* __restrict__ rowb, float* __restrict__ colb,
    u16* rowh, u16* rowl, u16* colh, u16* coll,
    float* __restrict__ dataT,
    u16* qh, u16* ql, u16* kh, u16* kl_, u16* vh, u16* vl,
    u16* ch, u16* cl, u16* f1h, u16* f1l, u16* f2h, u16* f2l) {
    __shared__ PrepS ps;
    int bid = blockIdx.x;
    int t = threadIdx.x;
    if (bid < 64) {
        // minmax stage-1 partials
        int b = bid >> 4, p = bid & 15;
        const float* src = data + (size_t)b * NN * NN + p * 4096;
        float lmin = 1e30f, lmax = -1e30f;
        #pragma unroll
        for (int i = 0; i < 16; i++) {
            float v = src[t + i * 256];
            lmin = fminf(lmin, v);
            lmax = fmaxf(lmax, v);
        }
        #pragma unroll
        for (int off = 32; off; off >>= 1) {
            lmin = fminf(lmin, __shfl_down(lmin, off));
            lmax = fmaxf(lmax, __shfl_down(lmax, off));
        }
        int wid = t >> 6, lane = t & 63;
        if (lane == 0) { ps.mm.smin[wid] = lmin; ps.mm.smax[wid] = lmax; }
        __syncthreads();
        if (t == 0) {
            pmin[b * 16 + p] = fminf(fminf(ps.mm.smin[0], ps.mm.smin[1]), fminf(ps.mm.smin[2], ps.mm.smin[3]));
            pmax[b * 16 + p] = fmaxf(fmaxf(ps.mm.smax[0], ps.mm.smax[1]), fmaxf(ps.mm.smax[2], ps.mm.smax[3]));
        }
    } else if (bid < 1088) {
        int idx = (bid - 64) * 256 + t;
        int bn = idx >> 8, e = idx & 255;
        float v = node_rand[bn] * Wnode[e] + bnode[e];
        rowb[idx] = v;
        colb[idx] = v;
        u16 h, l;
        bsplit(v, h, l);
        rowh[idx] = h; rowl[idx] = l;
        colh[idx] = h; coll[idx] = l;
    } else if (bid < 1344) {
        int local = bid - 1088;
        int bx = local & 7, by = (local >> 3) & 7, b = local >> 6;
        int r0 = by * 32, c0 = bx * 32;
        int tx = t & 31, ty = t >> 5;
        const float* src = data + (size_t)b * NN * NN;
        float* dst = dataT + (size_t)b * NN * NN;
        #pragma unroll
        for (int i = 0; i < 4; i++)
            ps.tile[(ty + 8 * i) * 33 + tx] = src[(size_t)(r0 + ty + 8 * i) * NN + c0 + tx];
        __syncthreads();
        #pragma unroll
        for (int i = 0; i < 4; i++)
            dst[(size_t)(c0 + ty + 8 * i) * NN + r0 + tx] = ps.tile[tx * 33 + ty + 8 * i];
    } else if (bid < 3904) {
        int id = bid - 1344;
        const float* W; u16 *Dh, *Dl; int K, N, mat, s, nt;
        if (id < 1280) {
            int seg = id / 320, local = id % 320;
            mat = local >> 5; int rem = local & 31; s = rem >> 2; nt = rem & 3;
            K = 256; N = 256;
            W  = seg == 0 ? Wq : seg == 1 ? Wk : seg == 2 ? Wv : Wc;
            Dh = seg == 0 ? qh : seg == 1 ? kh : seg == 2 ? vh : ch;
            Dl = seg == 0 ? ql : seg == 1 ? kl_ : seg == 2 ? vl : cl;
        } else if (id < 1920) {
            int local = id - 1280;
            mat = local >> 6; int rem = local & 63; s = rem >> 3; nt = rem & 7;
            K = 256; N = 512; W = W1; Dh = f1h; Dl = f1l;
        } else {
            int local = id - 1920;
            mat = local >> 6; int rem = local & 63; s = rem >> 2; nt = rem & 3;
            K = 512; N = 256; W = W2; Dh = f2h; Dl = f2l;
        }
        int kk = t >> 3, nl = (t & 7) * 8;
        const float* p = W + (size_t)mat * K * N + (size_t)(s * 32 + kk) * N + nt * 64 + nl;
        float4 f0 = *(const float4*)p;
        float4 f1v = *(const float4*)(p + 4);
        float fv[8] = {f0.x, f0.y, f0.z, f0.w, f1v.x, f1v.y, f1v.z, f1v.w};
        #pragma unroll
        for (int i = 0; i < 8; i++) bsplit(fv[i], ps.wp.th[(nl + i) * 40 + kk], ps.wp.tl[(nl + i) * 40 + kk]);
        __syncthreads();
        int n = t >> 2, ko = (t & 3) * 8;
        size_t dbase = (size_t)mat * K * N + (size_t)s * N * 32 + (size_t)nt * 64 * 32
                     + (size_t)n * 32 + ko;
        *(us8*)(Dh + dbase) = *(const us8*)&ps.wp.th[n * 40 + ko];
        *(us8*)(Dl + dbase) = *(const us8*)&ps.wp.tl[n * 40 + ko];
    } else {
        // mix constants: c1[lj,h] = sum_e Wedge[e]*Wmix[lj,e,h]; c0 likewise with bedge
        if (t < LAYERS * 2 * H) {
            int lj = t >> 4, h = t & 15;
            float c1 = 0.f, c0 = 0.f;
            for (int e = 0; e < E; e++) {
                float wm = Wmix[(lj * E + e) * H + h];
                c1 += Wedge[e] * wm;
                c0 += bedge[e] * wm;
            }
            c1c0[t] = c1;
            c1c0[160 + t] = c0;
        }
    }
}

// ================= LDS-staged MFMA GEMM, M=32 x N=64 tile, BK=128 =================
// hm=1: bf16 outputs permuted to head-major [b][h][m][d].
__device__ __forceinline__ void mfma_gemm(const u16* __restrict__ Ah, const u16* __restrict__ Al,
                                          const u16* __restrict__ Bh, const u16* __restrict__ Bl,
                                          const float* __restrict__ bias, const float* __restrict__ R,
                                          float* __restrict__ Cf, u16* __restrict__ Ch,
                                          u16* __restrict__ Cl, int K, int Ncols, int relu, int hm) {
    __shared__ u16 AsH[32 * 136], AsL[32 * 136], BsH[64 * 136], BsL[64 * 136];
    int t = threadIdx.x;
    int lane = t & 63, wave = t >> 6;
    int quad = lane >> 4, l16 = lane & 15;
    int wy = wave >> 1, wx = wave & 1;
    int mBase = blockIdx.x * 32, nBase = blockIdx.y * 64;
    f32x4 acc0 = {0.f, 0.f, 0.f, 0.f}, acc1 = acc0;
    int arow = t >> 3, ak = (t & 7) * 16;
    int bcol = lane, bq = wave;
    const int nslab = K >> 7;   // BK=128
    const u16* apH = Ah + (size_t)(mBase + arow) * K + ak;
    const u16* apL = Al + (size_t)(mBase + arow) * K + ak;
    const size_t sstr = (size_t)Ncols * 32;
    size_t bbase = (size_t)bq * sstr + (size_t)(nBase + bcol) * 32;
    const u16* bpH = Bh + bbase;
    const u16* bpL = Bl + bbase;
    us8 rah0 = *(const us8*)apH, rah1 = *(const us8*)(apH + 8);
    us8 ral0 = *(const us8*)apL, ral1 = *(const us8*)(apL + 8);
    us8 rbh0 = *(const us8*)(bpH + 0);
    us8 rbh1 = *(const us8*)(bpH + 8);
    us8 rbh2 = *(const us8*)(bpH + 16);
    us8 rbh3 = *(const us8*)(bpH + 24);
    us8 rbl0 = *(const us8*)(bpL + 0);
    us8 rbl1 = *(const us8*)(bpL + 8);
    us8 rbl2 = *(const us8*)(bpL + 16);
    us8 rbl3 = *(const us8*)(bpL + 24);
    for (int s = 0; s < nslab; s++) {
        __syncthreads();
        *(us8*)&AsH[arow * 136 + ak] = rah0;  *(us8*)&AsH[arow * 136 + ak + 8] = rah1;
        *(us8*)&AsL[arow * 136 + ak] = ral0;  *(us8*)&AsL[arow * 136 + ak + 8] = ral1;
        {
            int bb = bcol * 136 + bq * 32;
            *(us8*)&BsH[bb + 0] = rbh0;  *(us8*)&BsH[bb + 8] = rbh1;
            *(us8*)&BsH[bb + 16] = rbh2; *(us8*)&BsH[bb + 24] = rbh3;
            *(us8*)&BsL[bb + 0] = rbl0;  *(us8*)&BsL[bb + 8] = rbl1;
            *(us8*)&BsL[bb + 16] = rbl2; *(us8*)&BsL[bb + 24] = rbl3;
        }
        __syncthreads();
        if (s + 1 < nslab) {
            rah0 = *(const us8*)(apH + (s + 1) * 128);
            rah1 = *(const us8*)(apH + (s + 1) * 128 + 8);
            ral0 = *(const us8*)(apL + (s + 1) * 128);
            ral1 = *(const us8*)(apL + (s + 1) * 128 + 8);
            const u16* nbH = bpH + (size_t)(4 * (s + 1)) * sstr;
            const u16* nbL = bpL + (size_t)(4 * (s + 1)) * sstr;
            rbh0 = *(const us8*)(nbH + 0);  rbh1 = *(const us8*)(nbH + 8);
            rbh2 = *(const us8*)(nbH + 16); rbh3 = *(const us8*)(nbH + 24);
            rbl0 = *(const us8*)(nbL + 0);  rbl1 = *(const us8*)(nbL + 8);
            rbl2 = *(const us8*)(nbL + 16); rbl3 = *(const us8*)(nbL + 24);
        }
        #pragma unroll
        for (int c = 0; c < 4; c++) {
            bfrag a_h = *(const bfrag*)&AsH[(wy * 16 + l16) * 136 + c * 32 + quad * 8];
            bfrag a_l = *(const bfrag*)&AsL[(wy * 16 + l16) * 136 + c * 32 + quad * 8];
            bfrag b_h0 = *(const bfrag*)&BsH[(wx * 32 + l16) * 136 + c * 32 + quad * 8];
            bfrag b_h1 = *(const bfrag*)&BsH[(wx * 32 + 16 + l16) * 136 + c * 32 + quad * 8];
            bfrag b_l0 = *(const bfrag*)&BsL[(wx * 32 + l16) * 136 + c * 32 + quad * 8];
            bfrag b_l1 = *(const bfrag*)&BsL[(wx * 32 + 16 + l16) * 136 + c * 32 + quad * 8];
            acc0 = __builtin_amdgcn_mfma_f32_16x16x32_bf16(a_h, b_h0, acc0, 0, 0, 0);
            acc1 = __builtin_amdgcn_mfma_f32_16x16x32_bf16(a_h, b_h1, acc1, 0, 0, 0);
            acc0 = __builtin_amdgcn_mfma_f32_16x16x32_bf16(a_h, b_l0, acc0, 0, 0, 0);
            acc1 = __builtin_amdgcn_mfma_f32_16x16x32_bf16(a_h, b_l1, acc1, 0, 0, 0);
            acc0 = __builtin_amdgcn_mfma_f32_16x16x32_bf16(a_l, b_h0, acc0, 0, 0, 0);
            acc1 = __builtin_amdgcn_mfma_f32_16x16x32_bf16(a_l, b_h1, acc1, 0, 0, 0);
        }
    }
    int col0 = nBase + wx * 32 + l16;
    int col1 = col0 + 16;
    float bia0 = bias ? bias[col0] : 0.f;
    float bia1 = bias ? bias[col1] : 0.f;
    #pragma unroll
    for (int r = 0; r < 4; r++) {
        int row0 = mBase + wy * 16 + quad * 4 + r;
        float v0 = acc0[r] + bia0, v1 = acc1[r] + bia1;
        if (R) {
            v0 += R[(size_t)row0 * Ncols + col0];
            v1 += R[(size_t)row0 * Ncols + col1];
        }
        if (relu) {
            v0 = fmaxf(v0, 0.f); v1 = fmaxf(v1, 0.f);
        }
        if (Cf) {
            Cf[(size_t)row0 * Ncols + col0] = v0;
            Cf[(size_t)row0 * Ncols + col1] = v1;
        } else {
            size_t i0, i1;
            if (hm) {
                i0 = ((((size_t)(row0 >> 8) * 16 + (col0 >> 4)) * 256 + (row0 & 255)) * 16) + (col0 & 15);
                i1 = ((((size_t)(row0 >> 8) * 16 + (col1 >> 4)) * 256 + (row0 & 255)) * 16) + (col1 & 15);
            } else {
                i0 = (size_t)row0 * Ncols + col0;
                i1 = (size_t)row0 * Ncols + col1;
            }
            u16 h, l;
            bsplit(v0, h, l); Ch[i0] = h; Cl[i0] = l;
            bsplit(v1, h, l); Ch[i1] = h; Cl[i1] = l;
        }
    }
}

// z = j*3 + which(q/k/v); grid (32,4,6); outputs head-major bf16 hi/lo.
__global__ __launch_bounds__(256) void k_qkv(const u16* __restrict__ rowh, const u16* __restrict__ rowl,
                                             const u16* __restrict__ colh, const u16* __restrict__ coll,
                                             const u16* __restrict__ WqTh, const u16* __restrict__ WqTl,
                                             const u16* __restrict__ WkTh, const u16* __restrict__ WkTl,
                                             const u16* __restrict__ WvTh, const u16* __restrict__ WvTl,
                                             int lb2,
                                             u16* qhh0, u16* qhl0, u16* khh0, u16* khl0, u16* vhh0, u16* vhl0,
                                             u16* qhh1, u16* qhl1, u16* khh1, u16* khl1, u16* vhh1, u16* vhl1) {
    int z = blockIdx.z;
    int j = z / 3, w = z % 3;
    const u16* Ah = (w == 0) ? (j ? colh : rowh) : (j ? rowh : colh);
    const u16* Al = (w == 0) ? (j ? coll : rowl) : (j ? rowl : coll);
    const u16* Wh = (w == 0 ? WqTh : (w == 1 ? WkTh : WvTh)) + (size_t)(lb2 + j) * E * E;
    const u16* Wl = (w == 0 ? WqTl : (w == 1 ? WkTl : WvTl)) + (size_t)(lb2 + j) * E * E;
    u16* outs_h[6] = {qhh0, khh0, vhh0, qhh1, khh1, vhh1};
    u16* outs_l[6] = {qhl0, khl0, vhl0, qhl1, khl1, vhl1};
    mfma_gemm(Ah, Al, Wh, Wl, nullptr, nullptr, nullptr, outs_h[z], outs_l[z], E, E, 0, 1);
}

__global__ __launch_bounds__(256) void k_mgemm(const u16* Ah0, const u16* Al0,
                                               const u16* Ah1, const u16* Al1,
                                               const u16* __restrict__ Bh, const u16* __restrict__ Bl,
                                               int lb2, long wstride,
                                               const float* __restrict__ biasl, int bstride,
                                               const float* R0, const float* R1,
                                               float* Cf0, float* Cf1,
                                               u16* Ch0, u16* Cl0, u16* Ch1, u16* Cl1,
                                               int K, int Ncols, int relu) {
    int j = blockIdx.z;
    mfma_gemm(j ? Ah1 : Ah0, j ? Al1 : Al0,
              Bh + (size_t)(lb2 + j) * wstride, Bl + (size_t)(lb2 + j) * wstride,
              biasl ? biasl + (size_t)j * bstride : nullptr,
              R0 ? (j ? R1 : R0) : nullptr,
              Cf0 ? (j ? Cf1 : Cf0) : nullptr,
              Ch0 ? (j ? Ch1 : Ch0) : nullptr,
              Cl0 ? (j ? Cl1 : Cl0) : nullptr,
              K, Ncols, relu, 0);
}

// ================= MFMA fused attention =================
// Round-13 structure (head-major inputs, double-buffered P) + edge PREFETCH:
// all 16 edge float4 are loaded into registers BEFORE the staging barrier, so
// their L2 latency drains alongside K/V staging instead of appearing 16x
// inside the serial S->exp->P->PV chunk chain. Bitwise-identical numerics.
__global__ __launch_bounds__(256) void k_attn(
    const u16* __restrict__ qh0, const u16* __restrict__ ql0,
    const u16* __restrict__ kh0, const u16* __restrict__ kl0,
    const u16* __restrict__ vh0, const u16* __restrict__ vl0,
    const u16* __restrict__ qh1, const u16* __restrict__ ql1,
    const u16* __restrict__ kh1, const u16* __restrict__ kl1,
    const u16* __restrict__ vh1, const u16* __restrict__ vl1,
    const float* __restrict__ data, const float* __restrict__ dataT,
    const float* __restrict__ pmin, const float* __restrict__ pmax,
    const float* __restrict__ c1c0, int lj_base,
    u16* __restrict__ atth0, u16* __restrict__ attl0,
    u16* __restrict__ atth1, u16* __restrict__ attl1) {
    __shared__ u16 Ks[256 * 40];    // [m][40]: 0-15 Kh, 16-31 Kl, pad 8
    __shared__ u16 VTh[16 * 264];   // [d][m] hi
    __shared__ u16 VTl[16 * 264];   // [d][m] lo
    __shared__ u16 Pw[4][2][2 * 16 * 40];  // per wave x 2 bufs

    int wgid = blockIdx.x;
    int r8 = wgid & 7;
    int qd = wgid >> 3;            // 0..63
    int nq = qd & 3;
    int bhj = r8 * 16 + (qd >> 2); // 0..127, bijective
    int bh = bhj >> 1;
    int j = bhj & 1;
    int b = bh >> 4, h = bh & 15;
    const u16* qh = j ? qh1 : qh0;
    const u16* ql = j ? ql1 : ql0;
    const u16* kh = j ? kh1 : kh0;
    const u16* kl = j ? kl1 : kl0;
    const u16* vh = j ? vh1 : vh0;
    const u16* vl = j ? vl1 : vl0;
    float mn = 1e30f, mx = -1e30f;
    #pragma unroll
    for (int p = 0; p < 16; p++) {
        mn = fminf(mn, pmin[b * 16 + p]);
        mx = fmaxf(mx, pmax[b * 16 + p]);
    }
    float rng = mx - mn;
    if (rng == 0.f) rng = 1.f;
    float inv = 1.f / rng;
    float c1p = inv * c1c0[(lj_base + j) * 16 + h];
    float c0p = c1c0[160 + (lj_base + j) * 16 + h] - mn * c1p;

    int t = threadIdx.x;
    int lane = t & 63, w = t >> 6;
    int l16 = lane & 15, g = lane >> 4;
    int nb = nq * 64 + w * 16;
    int n = nb + l16;

    // head-major base for this (b,h): contiguous [256][16]
    const size_t hmb = ((size_t)b * 16 + h) * 256 * 16;

    bfrag qbh, qbl;
    {
        size_t qoff = hmb + (size_t)n * 16 + (g & 1) * 8;
        qbh = *(const bfrag*)(qh + qoff);
        if (g < 2) {
            qbl = *(const bfrag*)(ql + qoff);
        } else {
            qbl = (bfrag)(short)0;
        }
    }

    // edge prefetch: all 16 tiles' float4 loaded BEFORE the staging barrier
    const float* pedge = (j ? dataT : data) + (size_t)b * NN * NN + (size_t)n * NN;
    float4 ped[16];
    #pragma unroll
    for (int mt = 0; mt < 16; mt++) ped[mt] = *(const float4*)&pedge[mt * 16 + g * 4];

    // staging: thread t = row m; reads are contiguous 32B/lane (coalesced)
    {
        size_t roff = hmb + (size_t)t * 16;
        us8 a = *(const us8*)(kh + roff);
        us8 bv = *(const us8*)(kh + roff + 8);
        us8 c = *(const us8*)(kl + roff);
        us8 d = *(const us8*)(kl + roff + 8);
        *(us8*)&Ks[t * 40 + 0] = a;   *(us8*)&Ks[t * 40 + 8] = bv;
        *(us8*)&Ks[t * 40 + 16] = c;  *(us8*)&Ks[t * 40 + 24] = d;
        us8 vh0v = *(const us8*)(vh + roff);
        us8 vh1v = *(const us8*)(vh + roff + 8);
        us8 vl0v = *(const us8*)(vl + roff);
        us8 vl1v = *(const us8*)(vl + roff + 8);
        #pragma unroll
        for (int d2 = 0; d2 < 8; d2++) {
            VTh[d2 * 264 + t] = vh0v[d2];
            VTh[(d2 + 8) * 264 + t] = vh1v[d2];
            VTl[d2 * 264 + t] = vl0v[d2];
            VTl[(d2 + 8) * 264 + t] = vl1v[d2];
        }
    }
    __syncthreads();

    f32x4 oacc = {0.f, 0.f, 0.f, 0.f};
    float sum = 0.f;
    int aoff = g * 8;

    #pragma unroll
    for (int c = 0; c < 8; c++) {         // 32-m chunks, P double-buffered
        u16* myPh = &Pw[w][c & 1][0];
        u16* myPl = &Pw[w][c & 1][16 * 40];
        #pragma unroll
        for (int tt = 0; tt < 2; tt++) {
            int mt = c * 2 + tt;
            int mrow = mt * 16 + l16;
            bfrag a1 = *(const bfrag*)&Ks[mrow * 40 + aoff];
            f32x4 sacc = {0.f, 0.f, 0.f, 0.f};
            sacc = __builtin_amdgcn_mfma_f32_16x16x32_bf16(a1, qbh, sacc, 0, 0, 0);
            sacc = __builtin_amdgcn_mfma_f32_16x16x32_bf16(a1, qbl, sacc, 0, 0, 0);
            float evf[4] = {ped[mt].x, ped[mt].y, ped[mt].z, ped[mt].w};
            u16 ph[4], pl[4];
            #pragma unroll
            for (int r = 0; r < 4; r++) {
                float s = sacc[r] * 0.25f + evf[r] * c1p + c0p;
                float e = __expf(s);
                sum += e;
                bsplit(e, ph[r], pl[r]);
            }
            ushort4 phv; phv.x = ph[0]; phv.y = ph[1]; phv.z = ph[2]; phv.w = ph[3];
            ushort4 plv; plv.x = pl[0]; plv.y = pl[1]; plv.z = pl[2]; plv.w = pl[3];
            *(ushort4*)&myPh[l16 * 40 + tt * 16 + g * 4] = phv;
            *(ushort4*)&myPl[l16 * 40 + tt * 16 + g * 4] = plv;
        }
        bfrag pbh = *(const bfrag*)&myPh[l16 * 40 + g * 8];
        bfrag pbl = *(const bfrag*)&myPl[l16 * 40 + g * 8];
        bfrag vah = *(const bfrag*)&VTh[l16 * 264 + c * 32 + g * 8];
        bfrag vaL = *(const bfrag*)&VTl[l16 * 264 + c * 32 + g * 8];
        oacc = __builtin_amdgcn_mfma_f32_16x16x32_bf16(vah, pbh, oacc, 0, 0, 0);
        oacc = __builtin_amdgcn_mfma_f32_16x16x32_bf16(vah, pbl, oacc, 0, 0, 0);
        oacc = __builtin_amdgcn_mfma_f32_16x16x32_bf16(vaL, pbh, oacc, 0, 0, 0);
    }
    sum += __shfl_xor(sum, 16);
    sum += __shfl_xor(sum, 32);
    float invs = 1.f / sum;
    u16 hh[4], ll[4];
    #pragma unroll
    for (int r = 0; r < 4; r++) bsplit(oacc[r] * invs, hh[r], ll[r]);
    size_t obase = ((size_t)(b * NN + n) * E) + h * DD + g * 4;
    u16* oh = (j ? atth1 : atth0) + obase;
    u16* ol = (j ? attl1 : attl0) + obase;
    ushort4 ohv; ohv.x = hh[0]; ohv.y = hh[1]; ohv.z = hh[2]; ohv.w = hh[3];
    ushort4 olv; olv.x = ll[0]; olv.y = ll[1]; olv.z = ll[2]; olv.w = ll[3];
    *(ushort4*)oh = ohv;
    *(ushort4*)ol = olv;
}

// ================= instance norm over node dim =================
__global__ __launch_bounds__(256) void k_inorm(const float* __restrict__ Y0, const float* __restrict__ Y1,
                                               const float* __restrict__ wl, const float* __restrict__ bl,
                                               int pstride,
                                               float* Of0, float* Of1,
                                               u16* Oh0, u16* Ol0, u16* Oh1, u16* Ol1,
                                               float* __restrict__ fout) {
    int b = blockIdx.x, j = blockIdx.y;
    int ec = blockIdx.z * 8;
    const float* Y = (j ? Y1 : Y0) + (size_t)b * NN * E;
    float* O = (j ? Of1 : Of0) + (size_t)b * NN * E;
    u16* Oh = (j ? Oh1 : Oh0) + (size_t)b * NN * E;
    u16* Ol = (j ? Ol1 : Ol0) + (size_t)b * NN * E;
    const float* w = wl + (size_t)j * pstride;
    const float* bb = bl + (size_t)j * pstride;
    int t = threadIdx.x;
    int et = t & 7, n0 = t >> 3;
    int e = ec + et;
    float vals[8];
    float s = 0.f, s2 = 0.f;
    #pragma unroll
    for (int kk = 0; kk < 8; kk++) {
        float v = Y[(size_t)(n0 + 32 * kk) * E + e];
        vals[kk] = v;
        s += v;
        s2 += v * v;
    }
    __shared__ float ps[32 * 9], ps2[32 * 9];
    ps[n0 * 9 + et] = s;
    ps2[n0 * 9 + et] = s2;
    __syncthreads();
    float st = 0.f, st2 = 0.f;
    #pragma unroll
    for (int kk = 0; kk < 32; kk++) { st += ps[kk * 9 + et]; st2 += ps2[kk * 9 + et]; }
    float mu = st * (1.f / NN);
    float var = fmaxf(st2 * (1.f / NN) - mu * mu, 0.f);
    float scale = w[e] * rsqrtf(var + 1e-5f);
    float shift = bb[e] - mu * scale;
    #pragma unroll
    for (int kk = 0; kk < 8; kk++) {
        float vv = vals[kk] * scale + shift;
        size_t idx = (size_t)(n0 + 32 * kk) * E + e;
        O[idx] = vv;
        u16 hh, ll;
        bsplit(vv, hh, ll);
        Oh[idx] = hh;
        Ol[idx] = ll;
        if (fout) fout[(size_t)j * (BB * NN * E) + (size_t)b * NN * E + idx] = vv;
    }
}

// ---------------- host ----------------

extern "C" void kernel_launch(void* const* d_in, const int* in_sizes, int n_in,
                              void* d_out, int out_size, void* d_ws, size_t ws_size,
                              hipStream_t stream) {
    const float* data      = (const float*)d_in[0];
    const float* node_rand = (const float*)d_in[1];
    const float* Wnode     = (const float*)d_in[2];
    const float* bnode     = (const float*)d_in[3];
    const float* Wedge     = (const float*)d_in[4];
    const float* bedge     = (const float*)d_in[5];
    const float* Wq        = (const float*)d_in[6];
    const float* Wk        = (const float*)d_in[7];
    const float* Wv        = (const float*)d_in[8];
    const float* Wcomb     = (const float*)d_in[9];
    const float* bcomb     = (const float*)d_in[10];
    const float* n1w       = (const float*)d_in[11];
    const float* n1b       = (const float*)d_in[12];
    const float* W1        = (const float*)d_in[13];
    const float* b1        = (const float*)d_in[14];
    const float* W2        = (const float*)d_in[15];
    const float* b2        = (const float*)d_in[16];
    const float* n2w       = (const float*)d_in[17];
    const float* n2b       = (const float*)d_in[18];
    const float* Wmix      = (const float*)d_in[19];
    float* out = (float*)d_out;  // (row, col) concat

    float* ws = (float*)d_ws;
    const size_t T = (size_t)MROWS * E;      // 262144
    const size_t TF = (size_t)MROWS * FFH;   // 524288
    float* dataT = ws + 0 * T;
    float* row   = ws + 1 * T;
    float* col   = ws + 2 * T;
    float* o1f0  = ws + 9 * T;
    float* o1f1  = ws + 10 * T;
    float* pmin  = ws + 11 * T;
    float* pmax  = pmin + 64;
    float* c1c0  = pmax + 64;
    u16* us = (u16*)(ws + 11 * T + 512);
    auto nxt = [&](size_t n) { u16* p = us; us += n; return p; };
    u16* rowh = nxt(T);  u16* rowl = nxt(T);
    u16* colh = nxt(T);  u16* coll = nxt(T);
    u16* atth0 = nxt(T); u16* attl0 = nxt(T);
    u16* atth1 = nxt(T); u16* attl1 = nxt(T);
    u16* o1h0 = nxt(T);  u16* o1l0 = nxt(T);
    u16* o1h1 = nxt(T);  u16* o1l1 = nxt(T);
    u16* ffhh0 = nxt(TF); u16* ffhl0 = nxt(TF);
    u16* ffhh1 = nxt(TF); u16* ffhl1 = nxt(TF);
    const size_t EE10 = (size_t)10 * E * E;
    const size_t EF10 = (size_t)10 * E * FFH;
    u16* WqTh = nxt(EE10); u16* WqTl = nxt(EE10);
    u16* WkTh = nxt(EE10); u16* WkTl = nxt(EE10);
    u16* WvTh = nxt(EE10); u16* WvTl = nxt(EE10);
    u16* WcTh = nxt(EE10); u16* WcTl = nxt(EE10);
    u16* W1Th = nxt(EF10); u16* W1Tl = nxt(EF10);
    u16* W2Th = nxt(EF10); u16* W2Tl = nxt(EF10);
    // head-major bf16 hi/lo q,k,v for the MFMA attention
    u16* qhh0 = nxt(T); u16* qhl0 = nxt(T);
    u16* khh0 = nxt(T); u16* khl0 = nxt(T);
    u16* vhh0 = nxt(T); u16* vhl0 = nxt(T);
    u16* qhh1 = nxt(T); u16* qhl1 = nxt(T);
    u16* khh1 = nxt(T); u16* khl1 = nxt(T);
    u16* vhh1 = nxt(T); u16* vhl1 = nxt(T);

    k_prep<<<3905, 256, 0, stream>>>(data, node_rand, Wnode, bnode,
                                     Wedge, bedge, Wmix,
                                     Wq, Wk, Wv, Wcomb, W1, W2,
                                     pmin, pmax, c1c0,
                                     row, col, rowh, rowl, colh, coll, dataT,
                                     WqTh, WqTl, WkTh, WkTl, WvTh, WvTl,
                                     WcTh, WcTl, W1Th, W1Tl, W2Th, W2Tl);

    for (int l = 0; l < LAYERS; l++) {
        int lb2 = l * 2;
        k_qkv<<<dim3(32, 4, 6), 256, 0, stream>>>(rowh, rowl, colh, coll,
                                                  WqTh, WqTl, WkTh, WkTl, WvTh, WvTl, lb2,
                                                  qhh0, qhl0, khh0, khl0, vhh0, vhl0,
                                                  qhh1, qhl1, khh1, khl1, vhh1, vhl1);
        k_attn<<<dim3(512), 256, 0, stream>>>(qhh0, qhl0, khh0, khl0, vhh0, vhl0,
                                              qhh1, qhl1, khh1, khl1, vhh1, vhl1,
                                              data, dataT, pmin, pmax, c1c0, lb2,
                                              atth0, attl0, atth1, attl1);
        k_mgemm<<<dim3(32, 4, 2), 256, 0, stream>>>(atth0, attl0, atth1, attl1,
                                                    WcTh, WcTl, lb2, (long)E * E,
                                                    bcomb, E,
                                                    row, col, o1f0 /*tmp y0*/, o1f1 /*tmp y1*/,
                                                    nullptr, nullptr, nullptr, nullptr,
                                                    E, E, 0);
        k_inorm<<<dim3(BB, 2, 32), 256, 0, stream>>>(o1f0, o1f1,
                                                     n1w + (size_t)lb2 * E, n1b + (size_t)lb2 * E, E,
                                                     o1f0, o1f1, o1h0, o1l0, o1h1, o1l1, nullptr);
        k_mgemm<<<dim3(32, 8, 2), 256, 0, stream>>>(o1h0, o1l0, o1h1, o1l1,
                                                    W1Th, W1Tl, lb2, (long)E * FFH,
                                                    b1, FFH,
                                                    nullptr, nullptr, nullptr, nullptr,
                                                    ffhh0, ffhl0, ffhh1, ffhl1,
                                                    E, FFH, 1);
        k_mgemm<<<dim3(32, 4, 2), 256, 0, stream>>>(ffhh0, ffhl0, ffhh1, ffhl1,
                                                    W2Th, W2Tl, lb2, (long)FFH * E,
                                                    b2, E,
                                                    o1f0, o1f1, row /*y2 tmp*/, col /*y2 tmp*/,
                                                    nullptr, nullptr, nullptr, nullptr,
                                                    FFH, E, 0);
        k_inorm<<<dim3(BB, 2, 32), 256, 0, stream>>>(row, col,
                                                     n2w + (size_t)lb2 * E, n2b + (size_t)lb2 * E, E,
                                                     row, col, rowh, rowl, colh, coll,
                                                     (l == LAYERS - 1) ? out : nullptr);
    }
}

// Round 15
// 351.140 us; speedup vs baseline: 1.0263x; 1.0263x over previous
//
#include <hip/hip_runtime.h>
#include <hip/hip_bf16.h>

#define E 256
#define H 16
#define DD 16
#define FFH 512
#define LAYERS 5
#define BB 4
#define NN 256
#define MROWS 1024  // B*N

typedef __attribute__((ext_vector_type(8))) short bfrag;
typedef __attribute__((ext_vector_type(4))) float f32x4;
typedef __attribute__((ext_vector_type(8))) unsigned short us8;
typedef unsigned short u16;

__device__ __forceinline__ void bsplit(float v, u16& h, u16& l) {
    unsigned u = __float_as_uint(v);
    u16 hh = (u16)((u + 0x7fffu + ((u >> 16) & 1u)) >> 16);
    float r = v - __uint_as_float((unsigned)hh << 16);
    unsigned u2 = __float_as_uint(r);
    h = hh;
    l = (u16)((u2 + 0x7fffu + ((u2 >> 16) & 1u)) >> 16);
}

// ================= fused prep (minmax | emb | dataT | wprep | mixconst) =================
union PrepS {
    float tile[32 * 33];
    struct { u16 th[64 * 40], tl[64 * 40]; } wp;
    struct { float smin[4], smax[4]; } mm;
};

__global__ __launch_bounds__(256) void k_prep(
    const float* __restrict__ data, const float* __restrict__ node_rand,
    const float* __restrict__ Wnode, const float* __restrict__ bnode,
    const float* __restrict__ Wedge, const float* __restrict__ bedge,
    const float* __restrict__ Wmix,
    const float* __restrict__ Wq, const float* __restrict__ Wk, const float* __restrict__ Wv,
    const float* __restrict__ Wc, const float* __restrict__ W1, const float* __restrict__ W2,
    float* __restrict__ pmin, float* __restrict__ pmax, float* __restrict__ c1c0,
    float* __restrict__ rowb, float* __restrict__ colb,
    u16* rowh, u16* rowl, u16* colh, u16* coll,
    float* __restrict__ dataT,
    u16* qh, u16* ql, u16* kh, u16* kl_, u16* vh, u16* vl,
    u16* ch, u16* cl, u16* f1h, u16* f1l, u16* f2h, u16* f2l) {
    __shared__ PrepS ps;
    int bid = blockIdx.x;
    int t = threadIdx.x;
    if (bid < 64) {
        // minmax stage-1 partials
        int b = bid >> 4, p = bid & 15;
        const float* src = data + (size_t)b * NN * NN + p * 4096;
        float lmin = 1e30f, lmax = -1e30f;
        #pragma unroll
        for (int i = 0; i < 16; i++) {
            float v = src[t + i * 256];
            lmin = fminf(lmin, v);
            lmax = fmaxf(lmax, v);
        }
        #pragma unroll
        for (int off = 32; off; off >>= 1) {
            lmin = fminf(lmin, __shfl_down(lmin, off));
            lmax = fmaxf(lmax, __shfl_down(lmax, off));
        }
        int wid = t >> 6, lane = t & 63;
        if (lane == 0) { ps.mm.smin[wid] = lmin; ps.mm.smax[wid] = lmax; }
        __syncthreads();
        if (t == 0) {
            pmin[b * 16 + p] = fminf(fminf(ps.mm.smin[0], ps.mm.smin[1]), fminf(ps.mm.smin[2], ps.mm.smin[3]));
            pmax[b * 16 + p] = fmaxf(fmaxf(ps.mm.smax[0], ps.mm.smax[1]), fmaxf(ps.mm.smax[2], ps.mm.smax[3]));
        }
    } else if (bid < 1088) {
        int idx = (bid - 64) * 256 + t;
        int bn = idx >> 8, e = idx & 255;
        float v = node_rand[bn] * Wnode[e] + bnode[e];
        rowb[idx] = v;
        colb[idx] = v;
        u16 h, l;
        bsplit(v, h, l);
        rowh[idx] = h; rowl[idx] = l;
        colh[idx] = h; coll[idx] = l;
    } else if (bid < 1344) {
        int local = bid - 1088;
        int bx = local & 7, by = (local >> 3) & 7, b = local >> 6;
        int r0 = by * 32, c0 = bx * 32;
        int tx = t & 31, ty = t >> 5;
        const float* src = data + (size_t)b * NN * NN;
        float* dst = dataT + (size_t)b * NN * NN;
        #pragma unroll
        for (int i = 0; i < 4; i++)
            ps.tile[(ty + 8 * i) * 33 + tx] = src[(size_t)(r0 + ty + 8 * i) * NN + c0 + tx];
        __syncthreads();
        #pragma unroll
        for (int i = 0; i < 4; i++)
            dst[(size_t)(c0 + ty + 8 * i) * NN + r0 + tx] = ps.tile[tx * 33 + ty + 8 * i];
    } else if (bid < 3904) {
        int id = bid - 1344;
        const float* W; u16 *Dh, *Dl; int K, N, mat, s, nt;
        if (id < 1280) {
            int seg = id / 320, local = id % 320;
            mat = local >> 5; int rem = local & 31; s = rem >> 2; nt = rem & 3;
            K = 256; N = 256;
            W  = seg == 0 ? Wq : seg == 1 ? Wk : seg == 2 ? Wv : Wc;
            Dh = seg == 0 ? qh : seg == 1 ? kh : seg == 2 ? vh : ch;
            Dl = seg == 0 ? ql : seg == 1 ? kl_ : seg == 2 ? vl : cl;
        } else if (id < 1920) {
            int local = id - 1280;
            mat = local >> 6; int rem = local & 63; s = rem >> 3; nt = rem & 7;
            K = 256; N = 512; W = W1; Dh = f1h; Dl = f1l;
        } else {
            int local = id - 1920;
            mat = local >> 6; int rem = local & 63; s = rem >> 2; nt = rem & 3;
            K = 512; N = 256; W = W2; Dh = f2h; Dl = f2l;
        }
        int kk = t >> 3, nl = (t & 7) * 8;
        const float* p = W + (size_t)mat * K * N + (size_t)(s * 32 + kk) * N + nt * 64 + nl;
        float4 f0 = *(const float4*)p;
        float4 f1v = *(const float4*)(p + 4);
        float fv[8] = {f0.x, f0.y, f0.z, f0.w, f1v.x, f1v.y, f1v.z, f1v.w};
        #pragma unroll
        for (int i = 0; i < 8; i++) bsplit(fv[i], ps.wp.th[(nl + i) * 40 + kk], ps.wp.tl[(nl + i) * 40 + kk]);
        __syncthreads();
        int n = t >> 2, ko = (t & 3) * 8;
        size_t dbase = (size_t)mat * K * N + (size_t)s * N * 32 + (size_t)nt * 64 * 32
                     + (size_t)n * 32 + ko;
        *(us8*)(Dh + dbase) = *(const us8*)&ps.wp.th[n * 40 + ko];
        *(us8*)(Dl + dbase) = *(const us8*)&ps.wp.tl[n * 40 + ko];
    } else {
        // mix constants: c1[lj,h] = sum_e Wedge[e]*Wmix[lj,e,h]; c0 likewise with bedge
        if (t < LAYERS * 2 * H) {
            int lj = t >> 4, h = t & 15;
            float c1 = 0.f, c0 = 0.f;
            for (int e = 0; e < E; e++) {
                float wm = Wmix[(lj * E + e) * H + h];
                c1 += Wedge[e] * wm;
                c0 += bedge[e] * wm;
            }
            c1c0[t] = c1;
            c1c0[160 + t] = c0;
        }
    }
}

// ================= LDS-staged MFMA GEMM, M=32 x N=64 tile, BK=128 =================
// hm=1: bf16 outputs permuted to head-major [b][h][m][d].
__device__ __forceinline__ void mfma_gemm(const u16* __restrict__ Ah, const u16* __restrict__ Al,
                                          const u16* __restrict__ Bh, const u16* __restrict__ Bl,
                                          const float* __restrict__ bias, const float* __restrict__ R,
                                          float* __restrict__ Cf, u16* __restrict__ Ch,
                                          u16* __restrict__ Cl, int K, int Ncols, int relu, int hm) {
    __shared__ u16 AsH[32 * 136], AsL[32 * 136], BsH[64 * 136], BsL[64 * 136];
    int t = threadIdx.x;
    int lane = t & 63, wave = t >> 6;
    int quad = lane >> 4, l16 = lane & 15;
    int wy = wave >> 1, wx = wave & 1;
    int mBase = blockIdx.x * 32, nBase = blockIdx.y * 64;
    f32x4 acc0 = {0.f, 0.f, 0.f, 0.f}, acc1 = acc0;
    int arow = t >> 3, ak = (t & 7) * 16;
    int bcol = lane, bq = wave;
    const int nslab = K >> 7;   // BK=128
    const u16* apH = Ah + (size_t)(mBase + arow) * K + ak;
    const u16* apL = Al + (size_t)(mBase + arow) * K + ak;
    const size_t sstr = (size_t)Ncols * 32;
    size_t bbase = (size_t)bq * sstr + (size_t)(nBase + bcol) * 32;
    const u16* bpH = Bh + bbase;
    const u16* bpL = Bl + bbase;
    us8 rah0 = *(const us8*)apH, rah1 = *(const us8*)(apH + 8);
    us8 ral0 = *(const us8*)apL, ral1 = *(const us8*)(apL + 8);
    us8 rbh0 = *(const us8*)(bpH + 0);
    us8 rbh1 = *(const us8*)(bpH + 8);
    us8 rbh2 = *(const us8*)(bpH + 16);
    us8 rbh3 = *(const us8*)(bpH + 24);
    us8 rbl0 = *(const us8*)(bpL + 0);
    us8 rbl1 = *(const us8*)(bpL + 8);
    us8 rbl2 = *(const us8*)(bpL + 16);
    us8 rbl3 = *(const us8*)(bpL + 24);
    for (int s = 0; s < nslab; s++) {
        __syncthreads();
        *(us8*)&AsH[arow * 136 + ak] = rah0;  *(us8*)&AsH[arow * 136 + ak + 8] = rah1;
        *(us8*)&AsL[arow * 136 + ak] = ral0;  *(us8*)&AsL[arow * 136 + ak + 8] = ral1;
        {
            int bb = bcol * 136 + bq * 32;
            *(us8*)&BsH[bb + 0] = rbh0;  *(us8*)&BsH[bb + 8] = rbh1;
            *(us8*)&BsH[bb + 16] = rbh2; *(us8*)&BsH[bb + 24] = rbh3;
            *(us8*)&BsL[bb + 0] = rbl0;  *(us8*)&BsL[bb + 8] = rbl1;
            *(us8*)&BsL[bb + 16] = rbl2; *(us8*)&BsL[bb + 24] = rbl3;
        }
        __syncthreads();
        if (s + 1 < nslab) {
            rah0 = *(const us8*)(apH + (s + 1) * 128);
            rah1 = *(const us8*)(apH + (s + 1) * 128 + 8);
            ral0 = *(const us8*)(apL + (s + 1) * 128);
            ral1 = *(const us8*)(apL + (s + 1) * 128 + 8);
            const u16* nbH = bpH + (size_t)(4 * (s + 1)) * sstr;
            const u16* nbL = bpL + (size_t)(4 * (s + 1)) * sstr;
            rbh0 = *(const us8*)(nbH + 0);  rbh1 = *(const us8*)(nbH + 8);
            rbh2 = *(const us8*)(nbH + 16); rbh3 = *(const us8*)(nbH + 24);
            rbl0 = *(const us8*)(nbL + 0);  rbl1 = *(const us8*)(nbL + 8);
            rbl2 = *(const us8*)(nbL + 16); rbl3 = *(const us8*)(nbL + 24);
        }
        #pragma unroll
        for (int c = 0; c < 4; c++) {
            bfrag a_h = *(const bfrag*)&AsH[(wy * 16 + l16) * 136 + c * 32 + quad * 8];
            bfrag a_l = *(const bfrag*)&AsL[(wy * 16 + l16) * 136 + c * 32 + quad * 8];
            bfrag b_h0 = *(const bfrag*)&BsH[(wx * 32 + l16) * 136 + c * 32 + quad * 8];
            bfrag b_h1 = *(const bfrag*)&BsH[(wx * 32 + 16 + l16) * 136 + c * 32 + quad * 8];
            bfrag b_l0 = *(const bfrag*)&BsL[(wx * 32 + l16) * 136 + c * 32 + quad * 8];
            bfrag b_l1 = *(const bfrag*)&BsL[(wx * 32 + 16 + l16) * 136 + c * 32 + quad * 8];
            acc0 = __builtin_amdgcn_mfma_f32_16x16x32_bf16(a_h, b_h0, acc0, 0, 0, 0);
            acc1 = __builtin_amdgcn_mfma_f32_16x16x32_bf16(a_h, b_h1, acc1, 0, 0, 0);
            acc0 = __builtin_amdgcn_mfma_f32_16x16x32_bf16(a_h, b_l0, acc0, 0, 0, 0);
            acc1 = __builtin_amdgcn_mfma_f32_16x16x32_bf16(a_h, b_l1, acc1, 0, 0, 0);
            acc0 = __builtin_amdgcn_mfma_f32_16x16x32_bf16(a_l, b_h0, acc0, 0, 0, 0);
            acc1 = __builtin_amdgcn_mfma_f32_16x16x32_bf16(a_l, b_h1, acc1, 0, 0, 0);
        }
    }
    int col0 = nBase + wx * 32 + l16;
    int col1 = col0 + 16;
    float bia0 = bias ? bias[col0] : 0.f;
    float bia1 = bias ? bias[col1] : 0.f;
    #pragma unroll
    for (int r = 0; r < 4; r++) {
        int row0 = mBase + wy * 16 + quad * 4 + r;
        float v0 = acc0[r] + bia0, v1 = acc1[r] + bia1;
        if (R) {
            v0 += R[(size_t)row0 * Ncols + col0];
            v1 += R[(size_t)row0 * Ncols + col1];
        }
        if (relu) {
            v0 = fmaxf(v0, 0.f); v1 = fmaxf(v1, 0.f);
        }
        if (Cf) {
            Cf[(size_t)row0 * Ncols + col0] = v0;
            Cf[(size_t)row0 * Ncols + col1] = v1;
        } else {
            size_t i0, i1;
            if (hm) {
                i0 = ((((size_t)(row0 >> 8) * 16 + (col0 >> 4)) * 256 + (row0 & 255)) * 16) + (col0 & 15);
                i1 = ((((size_t)(row0 >> 8) * 16 + (col1 >> 4)) * 256 + (row0 & 255)) * 16) + (col1 & 15);
            } else {
                i0 = (size_t)row0 * Ncols + col0;
                i1 = (size_t)row0 * Ncols + col1;
            }
            u16 h, l;
            bsplit(v0, h, l); Ch[i0] = h; Cl[i0] = l;
            bsplit(v1, h, l); Ch[i1] = h; Cl[i1] = l;
        }
    }
}

// z = j*3 + which(q/k/v); grid (32,4,6); outputs head-major bf16 hi/lo.
__global__ __launch_bounds__(256) void k_qkv(const u16* __restrict__ rowh, const u16* __restrict__ rowl,
                                             const u16* __restrict__ colh, const u16* __restrict__ coll,
                                             const u16* __restrict__ WqTh, const u16* __restrict__ WqTl,
                                             const u16* __restrict__ WkTh, const u16* __restrict__ WkTl,
                                             const u16* __restrict__ WvTh, const u16* __restrict__ WvTl,
                                             int lb2,
                                             u16* qhh0, u16* qhl0, u16* khh0, u16* khl0, u16* vhh0, u16* vhl0,
                                             u16* qhh1, u16* qhl1, u16* khh1, u16* khl1, u16* vhh1, u16* vhl1) {
    int z = blockIdx.z;
    int j = z / 3, w = z % 3;
    const u16* Ah = (w == 0) ? (j ? colh : rowh) : (j ? rowh : colh);
    const u16* Al = (w == 0) ? (j ? coll : rowl) : (j ? rowl : coll);
    const u16* Wh = (w == 0 ? WqTh : (w == 1 ? WkTh : WvTh)) + (size_t)(lb2 + j) * E * E;
    const u16* Wl = (w == 0 ? WqTl : (w == 1 ? WkTl : WvTl)) + (size_t)(lb2 + j) * E * E;
    u16* outs_h[6] = {qhh0, khh0, vhh0, qhh1, khh1, vhh1};
    u16* outs_l[6] = {qhl0, khl0, vhl0, qhl1, khl1, vhl1};
    mfma_gemm(Ah, Al, Wh, Wl, nullptr, nullptr, nullptr, outs_h[z], outs_l[z], E, E, 0, 1);
}

__global__ __launch_bounds__(256) void k_mgemm(const u16* Ah0, const u16* Al0,
                                               const u16* Ah1, const u16* Al1,
                                               const u16* __restrict__ Bh, const u16* __restrict__ Bl,
                                               int lb2, long wstride,
                                               const float* __restrict__ biasl, int bstride,
                                               const float* R0, const float* R1,
                                               float* Cf0, float* Cf1,
                                               u16* Ch0, u16* Cl0, u16* Ch1, u16* Cl1,
                                               int K, int Ncols, int relu) {
    int j = blockIdx.z;
    mfma_gemm(j ? Ah1 : Ah0, j ? Al1 : Al0,
              Bh + (size_t)(lb2 + j) * wstride, Bl + (size_t)(lb2 + j) * wstride,
              biasl ? biasl + (size_t)j * bstride : nullptr,
              R0 ? (j ? R1 : R0) : nullptr,
              Cf0 ? (j ? Cf1 : Cf0) : nullptr,
              Ch0 ? (j ? Ch1 : Ch0) : nullptr,
              Cl0 ? (j ? Cl1 : Cl0) : nullptr,
              K, Ncols, relu, 0);
}

// ================= MFMA fused attention =================
// Round-13 proven structure: head-major q/k/v inputs (coalesced staging),
// B-side hi/lo zeroing (shared A-fragment), double-buffered P tiles.
__global__ __launch_bounds__(256) void k_attn(
    const u16* __restrict__ qh0, const u16* __restrict__ ql0,
    const u16* __restrict__ kh0, const u16* __restrict__ kl0,
    const u16* __restrict__ vh0, const u16* __restrict__ vl0,
    const u16* __restrict__ qh1, const u16* __restrict__ ql1,
    const u16* __restrict__ kh1, const u16* __restrict__ kl1,
    const u16* __restrict__ vh1, const u16* __restrict__ vl1,
    const float* __restrict__ data, const float* __restrict__ dataT,
    const float* __restrict__ pmin, const float* __restrict__ pmax,
    const float* __restrict__ c1c0, int lj_base,
    u16* __restrict__ atth0, u16* __restrict__ attl0,
    u16* __restrict__ atth1, u16* __restrict__ attl1) {
    __shared__ u16 Ks[256 * 40];    // [m][40]: 0-15 Kh, 16-31 Kl, pad 8
    __shared__ u16 VTh[16 * 264];   // [d][m] hi
    __shared__ u16 VTl[16 * 264];   // [d][m] lo
    __shared__ u16 Pw[4][2][2 * 16 * 40];  // per wave x 2 bufs

    int wgid = blockIdx.x;
    int r8 = wgid & 7;
    int qd = wgid >> 3;            // 0..63
    int nq = qd & 3;
    int bhj = r8 * 16 + (qd >> 2); // 0..127, bijective
    int bh = bhj >> 1;
    int j = bhj & 1;
    int b = bh >> 4, h = bh & 15;
    const u16* qh = j ? qh1 : qh0;
    const u16* ql = j ? ql1 : ql0;
    const u16* kh = j ? kh1 : kh0;
    const u16* kl = j ? kl1 : kl0;
    const u16* vh = j ? vh1 : vh0;
    const u16* vl = j ? vl1 : vl0;
    float mn = 1e30f, mx = -1e30f;
    #pragma unroll
    for (int p = 0; p < 16; p++) {
        mn = fminf(mn, pmin[b * 16 + p]);
        mx = fmaxf(mx, pmax[b * 16 + p]);
    }
    float rng = mx - mn;
    if (rng == 0.f) rng = 1.f;
    float inv = 1.f / rng;
    float c1p = inv * c1c0[(lj_base + j) * 16 + h];
    float c0p = c1c0[160 + (lj_base + j) * 16 + h] - mn * c1p;

    int t = threadIdx.x;
    int lane = t & 63, w = t >> 6;
    int l16 = lane & 15, g = lane >> 4;
    int nb = nq * 64 + w * 16;
    int n = nb + l16;

    // head-major base for this (b,h): contiguous [256][16]
    const size_t hmb = ((size_t)b * 16 + h) * 256 * 16;

    bfrag qbh, qbl;
    {
        size_t qoff = hmb + (size_t)n * 16 + (g & 1) * 8;
        qbh = *(const bfrag*)(qh + qoff);
        if (g < 2) {
            qbl = *(const bfrag*)(ql + qoff);
        } else {
            qbl = (bfrag)(short)0;
        }
    }

    // staging: thread t = row m; reads are contiguous 32B/lane (coalesced)
    {
        size_t roff = hmb + (size_t)t * 16;
        us8 a = *(const us8*)(kh + roff);
        us8 bv = *(const us8*)(kh + roff + 8);
        us8 c = *(const us8*)(kl + roff);
        us8 d = *(const us8*)(kl + roff + 8);
        *(us8*)&Ks[t * 40 + 0] = a;   *(us8*)&Ks[t * 40 + 8] = bv;
        *(us8*)&Ks[t * 40 + 16] = c;  *(us8*)&Ks[t * 40 + 24] = d;
        us8 vh0v = *(const us8*)(vh + roff);
        us8 vh1v = *(const us8*)(vh + roff + 8);
        us8 vl0v = *(const us8*)(vl + roff);
        us8 vl1v = *(const us8*)(vl + roff + 8);
        #pragma unroll
        for (int d2 = 0; d2 < 8; d2++) {
            VTh[d2 * 264 + t] = vh0v[d2];
            VTh[(d2 + 8) * 264 + t] = vh1v[d2];
            VTl[d2 * 264 + t] = vl0v[d2];
            VTl[(d2 + 8) * 264 + t] = vl1v[d2];
        }
    }
    __syncthreads();

    const float* pedge = (j ? dataT : data) + (size_t)b * NN * NN + (size_t)n * NN;
    f32x4 oacc = {0.f, 0.f, 0.f, 0.f};
    float sum = 0.f;
    int aoff = g * 8;

    #pragma unroll
    for (int c = 0; c < 8; c++) {         // 32-m chunks, P double-buffered
        u16* myPh = &Pw[w][c & 1][0];
        u16* myPl = &Pw[w][c & 1][16 * 40];
        #pragma unroll
        for (int tt = 0; tt < 2; tt++) {
            int mt = c * 2 + tt;
            int mrow = mt * 16 + l16;
            bfrag a1 = *(const bfrag*)&Ks[mrow * 40 + aoff];
            f32x4 sacc = {0.f, 0.f, 0.f, 0.f};
            sacc = __builtin_amdgcn_mfma_f32_16x16x32_bf16(a1, qbh, sacc, 0, 0, 0);
            sacc = __builtin_amdgcn_mfma_f32_16x16x32_bf16(a1, qbl, sacc, 0, 0, 0);
            float4 ev = *(const float4*)&pedge[mt * 16 + g * 4];
            float evf[4] = {ev.x, ev.y, ev.z, ev.w};
            u16 ph[4], pl[4];
            #pragma unroll
            for (int r = 0; r < 4; r++) {
                float s = sacc[r] * 0.25f + evf[r] * c1p + c0p;
                float e = __expf(s);
                sum += e;
                bsplit(e, ph[r], pl[r]);
            }
            ushort4 phv; phv.x = ph[0]; phv.y = ph[1]; phv.z = ph[2]; phv.w = ph[3];
            ushort4 plv; plv.x = pl[0]; plv.y = pl[1]; plv.z = pl[2]; plv.w = pl[3];
            *(ushort4*)&myPh[l16 * 40 + tt * 16 + g * 4] = phv;
            *(ushort4*)&myPl[l16 * 40 + tt * 16 + g * 4] = plv;
        }
        bfrag pbh = *(const bfrag*)&myPh[l16 * 40 + g * 8];
        bfrag pbl = *(const bfrag*)&myPl[l16 * 40 + g * 8];
        bfrag vah = *(const bfrag*)&VTh[l16 * 264 + c * 32 + g * 8];
        bfrag vaL = *(const bfrag*)&VTl[l16 * 264 + c * 32 + g * 8];
        oacc = __builtin_amdgcn_mfma_f32_16x16x32_bf16(vah, pbh, oacc, 0, 0, 0);
        oacc = __builtin_amdgcn_mfma_f32_16x16x32_bf16(vah, pbl, oacc, 0, 0, 0);
        oacc = __builtin_amdgcn_mfma_f32_16x16x32_bf16(vaL, pbh, oacc, 0, 0, 0);
    }
    sum += __shfl_xor(sum, 16);
    sum += __shfl_xor(sum, 32);
    float invs = 1.f / sum;
    u16 hh[4], ll[4];
    #pragma unroll
    for (int r = 0; r < 4; r++) bsplit(oacc[r] * invs, hh[r], ll[r]);
    size_t obase = ((size_t)(b * NN + n) * E) + h * DD + g * 4;
    u16* oh = (j ? atth1 : atth0) + obase;
    u16* ol = (j ? attl1 : attl0) + obase;
    ushort4 ohv; ohv.x = hh[0]; ohv.y = hh[1]; ohv.z = hh[2]; ohv.w = hh[3];
    ushort4 olv; olv.x = ll[0]; olv.y = ll[1]; olv.z = ll[2]; olv.w = ll[3];
    *(ushort4*)oh = ohv;
    *(ushort4*)ol = olv;
}

// ================= instance norm over node dim =================
__global__ __launch_bounds__(256) void k_inorm(const float* __restrict__ Y0, const float* __restrict__ Y1,
                                               const float* __restrict__ wl, const float* __restrict__ bl,
                                               int pstride,
                                               float* Of0, float* Of1,
                                               u16* Oh0, u16* Ol0, u16* Oh1, u16* Ol1,
                                               float* __restrict__ fout) {
    int b = blockIdx.x, j = blockIdx.y;
    int ec = blockIdx.z * 8;
    const float* Y = (j ? Y1 : Y0) + (size_t)b * NN * E;
    float* O = (j ? Of1 : Of0) + (size_t)b * NN * E;
    u16* Oh = (j ? Oh1 : Oh0) + (size_t)b * NN * E;
    u16* Ol = (j ? Ol1 : Ol0) + (size_t)b * NN * E;
    const float* w = wl + (size_t)j * pstride;
    const float* bb = bl + (size_t)j * pstride;
    int t = threadIdx.x;
    int et = t & 7, n0 = t >> 3;
    int e = ec + et;
    float vals[8];
    float s = 0.f, s2 = 0.f;
    #pragma unroll
    for (int kk = 0; kk < 8; kk++) {
        float v = Y[(size_t)(n0 + 32 * kk) * E + e];
        vals[kk] = v;
        s += v;
        s2 += v * v;
    }
    __shared__ float ps[32 * 9], ps2[32 * 9];
    ps[n0 * 9 + et] = s;
    ps2[n0 * 9 + et] = s2;
    __syncthreads();
    float st = 0.f, st2 = 0.f;
    #pragma unroll
    for (int kk = 0; kk < 32; kk++) { st += ps[kk * 9 + et]; st2 += ps2[kk * 9 + et]; }
    float mu = st * (1.f / NN);
    float var = fmaxf(st2 * (1.f / NN) - mu * mu, 0.f);
    float scale = w[e] * rsqrtf(var + 1e-5f);
    float shift = bb[e] - mu * scale;
    #pragma unroll
    for (int kk = 0; kk < 8; kk++) {
        float vv = vals[kk] * scale + shift;
        size_t idx = (size_t)(n0 + 32 * kk) * E + e;
        O[idx] = vv;
        u16 hh, ll;
        bsplit(vv, hh, ll);
        Oh[idx] = hh;
        Ol[idx] = ll;
        if (fout) fout[(size_t)j * (BB * NN * E) + (size_t)b * NN * E + idx] = vv;
    }
}

// ---------------- host ----------------

extern "C" void kernel_launch(void* const* d_in, const int* in_sizes, int n_in,
                              void* d_out, int out_size, void* d_ws, size_t ws_size,
                              hipStream_t stream) {
    const float* data      = (const float*)d_in[0];
    const float* node_rand = (const float*)d_in[1];
    const float* Wnode     = (const float*)d_in[2];
    const float* bnode     = (const float*)d_in[3];
    const float* Wedge     = (const float*)d_in[4];
    const float* bedge     = (const float*)d_in[5];
    const float* Wq        = (const float*)d_in[6];
    const float* Wk        = (const float*)d_in[7];
    const float* Wv        = (const float*)d_in[8];
    const float* Wcomb     = (const float*)d_in[9];
    const float* bcomb     = (const float*)d_in[10];
    const float* n1w       = (const float*)d_in[11];
    const float* n1b       = (const float*)d_in[12];
    const float* W1        = (const float*)d_in[13];
    const float* b1        = (const float*)d_in[14];
    const float* W2        = (const float*)d_in[15];
    const float* b2        = (const float*)d_in[16];
    const float* n2w       = (const float*)d_in[17];
    const float* n2b       = (const float*)d_in[18];
    const float* Wmix      = (const float*)d_in[19];
    float* out = (float*)d_out;  // (row, col) concat

    float* ws = (float*)d_ws;
    const size_t T = (size_t)MROWS * E;      // 262144
    const size_t TF = (size_t)MROWS * FFH;   // 524288
    float* dataT = ws + 0 * T;
    float* row   = ws + 1 * T;
    float* col   = ws + 2 * T;
    float* o1f0  = ws + 9 * T;
    float* o1f1  = ws + 10 * T;
    float* pmin  = ws + 11 * T;
    float* pmax  = pmin + 64;
    float* c1c0  = pmax + 64;
    u16* us = (u16*)(ws + 11 * T + 512);
    auto nxt = [&](size_t n) { u16* p = us; us += n; return p; };
    u16* rowh = nxt(T);  u16* rowl = nxt(T);
    u16* colh = nxt(T);  u16* coll = nxt(T);
    u16* atth0 = nxt(T); u16* attl0 = nxt(T);
    u16* atth1 = nxt(T); u16* attl1 = nxt(T);
    u16* o1h0 = nxt(T);  u16* o1l0 = nxt(T);
    u16* o1h1 = nxt(T);  u16* o1l1 = nxt(T);
    u16* ffhh0 = nxt(TF); u16* ffhl0 = nxt(TF);
    u16* ffhh1 = nxt(TF); u16* ffhl1 = nxt(TF);
    const size_t EE10 = (size_t)10 * E * E;
    const size_t EF10 = (size_t)10 * E * FFH;
    u16* WqTh = nxt(EE10); u16* WqTl = nxt(EE10);
    u16* WkTh = nxt(EE10); u16* WkTl = nxt(EE10);
    u16* WvTh = nxt(EE10); u16* WvTl = nxt(EE10);
    u16* WcTh = nxt(EE10); u16* WcTl = nxt(EE10);
    u16* W1Th = nxt(EF10); u16* W1Tl = nxt(EF10);
    u16* W2Th = nxt(EF10); u16* W2Tl = nxt(EF10);
    // head-major bf16 hi/lo q,k,v for the MFMA attention
    u16* qhh0 = nxt(T); u16* qhl0 = nxt(T);
    u16* khh0 = nxt(T); u16* khl0 = nxt(T);
    u16* vhh0 = nxt(T); u16* vhl0 = nxt(T);
    u16* qhh1 = nxt(T); u16* qhl1 = nxt(T);
    u16* khh1 = nxt(T); u16* khl1 = nxt(T);
    u16* vhh1 = nxt(T); u16* vhl1 = nxt(T);

    k_prep<<<3905, 256, 0, stream>>>(data, node_rand, Wnode, bnode,
                                     Wedge, bedge, Wmix,
                                     Wq, Wk, Wv, Wcomb, W1, W2,
                                     pmin, pmax, c1c0,
                                     row, col, rowh, rowl, colh, coll, dataT,
                                     WqTh, WqTl, WkTh, WkTl, WvTh, WvTl,
                                     WcTh, WcTl, W1Th, W1Tl, W2Th, W2Tl);

    for (int l = 0; l < LAYERS; l++) {
        int lb2 = l * 2;
        k_qkv<<<dim3(32, 4, 6), 256, 0, stream>>>(rowh, rowl, colh, coll,
                                                  WqTh, WqTl, WkTh, WkTl, WvTh, WvTl, lb2,
                                                  qhh0, qhl0, khh0, khl0, vhh0, vhl0,
                                                  qhh1, qhl1, khh1, khl1, vhh1, vhl1);
        k_attn<<<dim3(512), 256, 0, stream>>>(qhh0, qhl0, khh0, khl0, vhh0, vhl0,
                                              qhh1, qhl1, khh1, khl1, vhh1, vhl1,
                                              data, dataT, pmin, pmax, c1c0, lb2,
                                              atth0, attl0, atth1, attl1);
        k_mgemm<<<dim3(32, 4, 2), 256, 0, stream>>>(atth0, attl0, atth1, attl1,
                                                    WcTh, WcTl, lb2, (long)E * E,
                                                    bcomb, E,
                                                    row, col, o1f0 /*tmp y0*/, o1f1 /*tmp y1*/,
                                                    nullptr, nullptr, nullptr, nullptr,
                                                    E, E, 0);
        k_inorm<<<dim3(BB, 2, 32), 256, 0, stream>>>(o1f0, o1f1,
                                                     n1w + (size_t)lb2 * E, n1b + (size_t)lb2 * E, E,
                                                     o1f0, o1f1, o1h0, o1l0, o1h1, o1l1, nullptr);
        k_mgemm<<<dim3(32, 8, 2), 256, 0, stream>>>(o1h0, o1l0, o1h1, o1l1,
                                                    W1Th, W1Tl, lb2, (long)E * FFH,
                                                    b1, FFH,
                                                    nullptr, nullptr, nullptr, nullptr,
                                                    ffhh0, ffhl0, ffhh1, ffhl1,
                                                    E, FFH, 1);
        k_mgemm<<<dim3(32, 4, 2), 256, 0, stream>>>(ffhh0, ffhl0, ffhh1, ffhl1,
                                                    W2Th, W2Tl, lb2, (long)FFH * E,
                                                    b2, E,
                                                    o1f0, o1f1, row /*y2 tmp*/, col /*y2 tmp*/,
                                                    nullptr, nullptr, nullptr, nullptr,
                                                    FFH, E, 0);
        k_inorm<<<dim3(BB, 2, 32), 256, 0, stream>>>(row, col,
                                                     n2w + (size_t)lb2 * E, n2b + (size_t)lb2 * E, E,
                                                     row, col, rowh, rowl, colh, coll,
                                                     (l == LAYERS - 1) ? out : nullptr);
    }
}